// Round 14
// baseline (10332.141 us; speedup 1.0000x reference)
//
#include <hip/hip_runtime.h>
#include <hip/hip_bf16.h>
#include <hip/hip_fp16.h>

// Hypernetwork RNN scan. B=16, N=2048, M=H=64, L*E=1024, Cout=256.
// Round 14: ONE WG PER BATCH — the exchange is eliminated, not optimized.
// R4-R13 established the floor of any per-step cross-CU exchange at
// ~1300-2400 cyc (LLC visibility + sampling). Instead, one CU holds all of
// Wd via three tiers: 2 rows/thread in VGPRs (R12-proven), 2 rows/thread in
// LDS (128 KB), 4 rows/thread + encoder streamed from per-XCD L2 each step
// (static addresses -> L2-resident; ~144 B/cyc/CU measured). grid=16, no
// atomics, no polls; 3 syncthreads/step is the only synchronization.
//   K1 cvt: Wd->f16 1-WG layout; enc m-rows->f16; dec_w->bf16 (loss)
//   K2 build_T (f32, 8 MB), K3 build_P (f32, 16 MB)
//   K4 recur: 16 WGs x 512 thr; tiered Wd; wave-0 final; f16 m history
//   K5 loss:  parallel logits/LSE/NLL over the f16 m history

typedef unsigned int uint_t;
typedef unsigned short us_t;
typedef unsigned long long u64_t;
typedef _Float16 h2_t __attribute__((ext_vector_type(2)));

__device__ __forceinline__ us_t f2bf(float f) {
    uint_t u = __float_as_uint(f);
    uint_t r = u + 0x7fffu + ((u >> 16) & 1u);   // RNE
    return (us_t)(r >> 16);
}
__device__ __forceinline__ float bflo(uint_t u) { return __uint_as_float(u << 16); }
__device__ __forceinline__ float bfhi(uint_t u) { return __uint_as_float(u & 0xffff0000u); }

__device__ __forceinline__ us_t f2h(float f) {
    __half h = __float2half(f);                  // RNE
    return *reinterpret_cast<us_t*>(&h);
}
__device__ __forceinline__ float h2f(us_t s) {
    __half h = *reinterpret_cast<__half*>(&s);
    return __half2float(h);
}
__device__ __forceinline__ h2_t u2h2(uint_t u) {
    union { uint_t u; h2_t h; } x; x.u = u; return x.h;
}

#if __has_builtin(__builtin_amdgcn_fdot2)
__device__ __forceinline__ float dot2f(uint_t a, uint_t b, float c) {
    return __builtin_amdgcn_fdot2(u2h2(a), u2h2(b), c, false);
}
#else
__device__ __forceinline__ float dot2f(uint_t a, uint_t b, float c) {
    h2_t x = u2h2(a), y = u2h2(b);
    return c + (float)x.x * (float)y.x + (float)x.y * (float)y.y;
}
#endif

#define DOT4(q, base, acc)                                              \
    acc = dot2f(q.x, mreg2u[(base) + 0], acc);                          \
    acc = dot2f(q.y, mreg2u[(base) + 1], acc);                          \
    acc = dot2f(q.z, mreg2u[(base) + 2], acc);                          \
    acc = dot2f(q.w, mreg2u[(base) + 3], acc);

// ---------------- K1: convert/swizzle weights ----------------
// WdG [c<8][jp<8][tid<512][kk<8] f16: row o = c*512+tid, h=o>>6, i=o&63,
//     val = Wd[h][i*64 + jp*8 + kk]  (uint4 at (c*8+jp)*512+tid lane-contig)
// decwY [mm<64][lane<64][k<4] bf16: val = decw[mm*256 + k*64 + lane]
// EWmG [jp<8][h2<128][kk<8] f16: val = enc_m_row(j=jp*8+kk, h2)
__global__ void cvt_kernel(const float* __restrict__ Wdecw,
                           const float* __restrict__ decw,
                           const float* __restrict__ Wencw,
                           const float* __restrict__ bencw,
                           us_t* __restrict__ WdG, us_t* __restrict__ decwY,
                           us_t* __restrict__ EWmG) {
    int o = blockIdx.x * 256 + threadIdx.x;
    if (o < 262144) {
        int kk = o & 7;
        int tid = (o >> 3) & 511;
        int jp = (o >> 12) & 7;
        int c = o >> 15;
        int h = c * 8 + (tid >> 6);
        int i = tid & 63;
        int j = jp * 8 + kk;
        WdG[o] = f2h(Wdecw[h * 4096 + i * 64 + j]);
    } else if (o < 278528) {
        int oo = o - 262144;
        int k = oo & 3, lane = (oo >> 2) & 63, mm = oo >> 8;
        decwY[oo] = f2bf(decw[mm * 256 + k * 64 + lane]);
    } else if (o < 286720) {
        int oo = o - 278528;
        int kk = oo & 7, h2 = (oo >> 3) & 127, jp = oo >> 10;
        int j = jp * 8 + kk;
        float v = (h2 < 64) ? Wencw[j * 64 + h2] : bencw[j * 64 + (h2 - 64)];
        EWmG[oo] = f2h(v);
    }
}

// ---------------- K2: token contribution table ----------------
__global__ void build_T(const float* __restrict__ emb, const float* __restrict__ Wencw,
                        const float* __restrict__ bencw, float* __restrict__ T) {
    int l = blockIdx.x >> 8, v = blockIdx.x & 255, h2 = threadIdx.x;  // h2 < 128
    float acc = 0.f;
#pragma unroll
    for (int e = 0; e < 16; ++e) {
        int d = 64 + l * 16 + e;
        float w = (h2 < 64) ? Wencw[d * 64 + h2] : bencw[d * 64 + (h2 - 64)];
        acc += emb[v * 16 + e] * w;
    }
    T[blockIdx.x * 128 + h2] = acc;
}

// ---------------- K3: window precompute P (f32) ----------------
__global__ void build_P(const float* __restrict__ T, const int* __restrict__ x0,
                        const float* __restrict__ Wencb, const float* __restrict__ bencb,
                        float* __restrict__ P) {
    int t = blockIdx.x >> 4, b = blockIdx.x & 15, h2 = threadIdx.x;  // h2 < 128
    float acc = (h2 < 64) ? Wencb[h2] : bencb[h2 - 64];
    for (int l = 0; l < 64; ++l) {
        int p = t + l;
        int v = (p < 64) ? 0 : x0[b * 2048 + (p - 64)];
        acc += T[(l * 256 + v) * 128 + h2];
    }
    P[blockIdx.x * 128 + h2] = acc;
}

// ---------------- K4: sequential recurrence (1 WG per batch) -------------
// grid 16, 512 threads. Thread owns rows o = c*512+tid, c<8:
//   c=0,1 -> wreg (VGPR) | c=2,3 -> LDS | c=4..7 -> streamed from L2/step.
__global__ __launch_bounds__(512, 2) void recur(
    const float* __restrict__ bdecw, const float* __restrict__ bdecb,
    const float* __restrict__ Wdecb, const us_t* __restrict__ WdG,
    const us_t* __restrict__ EWmG, const float* __restrict__ P,
    uint_t* __restrict__ mh32) {
    const int b = blockIdx.x;
    const int tid = threadIdx.x;
    const int i = tid & 63, q = tid >> 6;

    extern __shared__ char smem[];
    float*  V_s    = (float*)(smem);            // 16384 B [o<4096] = [h][i]
    float*  rp8_s  = (float*)(smem + 16384);    // 2048 B  [q<8][i]
    float*  wmhb_s = (float*)(smem + 18432);    // 2048 B  [q<8][i]
    float*  hw_s   = (float*)(smem + 20480);    // 256 B
    uint_t* hb2_s  = (uint_t*)(smem + 20736);   // 128 B packed f16 hb pairs
    uint_t* m2_s   = (uint_t*)(smem + 20864);   // 128 B packed f16 m pairs
    float*  bias_s = (float*)(smem + 20992);    // 256 B
    us_t*   Wd_lds = (us_t*)(smem + 21248);     // 131072 B (rows c=2,3)
    // total 152320

    const uint4* g4 = (const uint4*)WdG;
    const uint4* EW4 = (const uint4*)EWmG;

    // ---- init: rows c=0,1 -> registers ----
    uint4 wreg[16];
#pragma unroll
    for (int jp = 0; jp < 8; ++jp) {
        wreg[jp]     = g4[jp * 512 + tid];          // c=0
        wreg[8 + jp] = g4[(8 + jp) * 512 + tid];    // c=1
    }
    // rows c=2,3 -> LDS
    {
        uint4* l4w = (uint4*)Wd_lds;
#pragma unroll
        for (int jp = 0; jp < 8; ++jp) {
            l4w[jp * 512 + tid]       = g4[(16 + jp) * 512 + tid];
            l4w[(8 + jp) * 512 + tid] = g4[(24 + jp) * 512 + tid];
        }
    }
    // phase-B weight slices (jj = q*4+k) -> registers
    uint_t wdbtreg[4], bdecreg[4];
#pragma unroll
    for (int k = 0; k < 4; ++k) {
        int jj = q * 4 + k;
        wdbtreg[k] = (uint_t)f2h(Wdecb[i * 64 + 2 * jj])
                   | ((uint_t)f2h(Wdecb[i * 64 + 2 * jj + 1]) << 16);
        bdecreg[k] = (uint_t)f2h(bdecw[(2 * jj) * 64 + i])
                   | ((uint_t)f2h(bdecw[(2 * jj + 1) * 64 + i]) << 16);
    }
    if (tid < 64) bias_s[tid] = bdecb[tid];
    if (tid < 32) m2_s[tid] = 0u;
    __syncthreads();

    // persistent packed-f16 m; COMPILE-TIME indexing only (R3 lesson).
    uint_t mreg2u[32];
#pragma unroll
    for (int j = 0; j < 32; ++j) mreg2u[j] = 0u;

    float preg = 0.f;
    if (tid < 128) preg = P[b * 128 + tid];  // t = 0

    const uint4* l4 = (const uint4*)Wd_lds;

    for (int t = 0; t < 2048; ++t) {
        // ---- phase A ----
        float pnext = 0.f;
        int tp = (t < 2047) ? (t + 1) : 2047;
        if (tid < 128) pnext = P[(tp * 16 + b) * 128 + tid];

        // stream rows c=4,5 (2 buffers; c=6,7 reissued mid-phase); enc rows
        uint4 sA[8], sB[8], eS[8];
#pragma unroll
        for (int jp = 0; jp < 8; ++jp) sA[jp] = g4[(32 + jp) * 512 + tid];
#pragma unroll
        for (int jp = 0; jp < 8; ++jp) sB[jp] = g4[(40 + jp) * 512 + tid];
        if (tid < 128) {
#pragma unroll
            for (int jp = 0; jp < 8; ++jp) eS[jp] = EW4[jp * 128 + tid];
        }

        float a0 = 0, a1 = 0, a2 = 0, a3 = 0, a4 = 0, a5 = 0, a6 = 0, a7 = 0;
#pragma unroll
        for (int jp = 0; jp < 8; ++jp) { uint4 v = wreg[jp];     DOT4(v, jp * 4, a0); }
#pragma unroll
        for (int jp = 0; jp < 8; ++jp) { uint4 v = wreg[8 + jp]; DOT4(v, jp * 4, a1); }
#pragma unroll
        for (int jp = 0; jp < 8; ++jp) { uint4 v = l4[jp * 512 + tid];       DOT4(v, jp * 4, a2); }
#pragma unroll
        for (int jp = 0; jp < 8; ++jp) { uint4 v = l4[(8 + jp) * 512 + tid]; DOT4(v, jp * 4, a3); }
#pragma unroll
        for (int jp = 0; jp < 8; ++jp) { DOT4(sA[jp], jp * 4, a4); }
#pragma unroll
        for (int jp = 0; jp < 8; ++jp) sA[jp] = g4[(48 + jp) * 512 + tid];  // c=6
#pragma unroll
        for (int jp = 0; jp < 8; ++jp) { DOT4(sB[jp], jp * 4, a5); }
#pragma unroll
        for (int jp = 0; jp < 8; ++jp) sB[jp] = g4[(56 + jp) * 512 + tid];  // c=7
#pragma unroll
        for (int jp = 0; jp < 8; ++jp) { DOT4(sA[jp], jp * 4, a6); }
#pragma unroll
        for (int jp = 0; jp < 8; ++jp) { DOT4(sB[jp], jp * 4, a7); }

        V_s[tid]        = a0;   // row o = c*512+tid = h*64+i (linear)
        V_s[512 + tid]  = a1;
        V_s[1024 + tid] = a2;
        V_s[1536 + tid] = a3;
        V_s[2048 + tid] = a4;
        V_s[2560 + tid] = a5;
        V_s[3072 + tid] = a6;
        V_s[3584 + tid] = a7;

        if (tid < 128) {
            float acc = preg;
#pragma unroll
            for (int jp = 0; jp < 8; ++jp) { DOT4(eS[jp], jp * 4, acc); }
            float sg = 1.f / (1.f + __expf(-acc));
            if (tid < 64) {
                hw_s[tid] = sg;
            } else {
                int l = tid - 64;
                float vlo = __shfl(sg, (l & 31) * 2, 64);
                float vhi = __shfl(sg, (l & 31) * 2 + 1, 64);
                if (l < 32)
                    hb2_s[l] = (uint_t)f2h(vlo) | ((uint_t)f2h(vhi) << 16);
            }
        }
        preg = pnext;
        __syncthreads();   // sync1

        // ---- phase B: all 8 waves; m/hb via LDS broadcast (runtime q ok) ----
        {
            float r = 0.f;
#pragma unroll
            for (int hh = 0; hh < 8; ++hh)
                r += hw_s[q * 8 + hh] * V_s[(q * 8 + hh) * 64 + i];
            rp8_s[q * 64 + i] = r;
            float wh = 0.f;
#pragma unroll
            for (int k = 0; k < 4; ++k) {
                wh = dot2f(wdbtreg[k], m2_s[q * 4 + k], wh);
                wh = dot2f(bdecreg[k], hb2_s[q * 4 + k], wh);
            }
            wmhb_s[q * 64 + i] = wh;
        }
        __syncthreads();   // sync2

        // ---- final: wave 0 assembles m, writes m2_s + history ----
        if (tid < 64) {
            float r = bias_s[tid];
#pragma unroll
            for (int qq = 0; qq < 8; ++qq) r += rp8_s[qq * 64 + tid];
#pragma unroll
            for (int qq = 0; qq < 8; ++qq) r += wmhb_s[qq * 64 + tid];
            float nm = 1.f / (1.f + __expf(-r));
            us_t nh = f2h(nm);
            uint_t nhu = (uint_t)nh;
            uint_t lo = (uint_t)__shfl((int)nhu, (tid & 31) * 2, 64);
            uint_t hi = (uint_t)__shfl((int)nhu, (tid & 31) * 2 + 1, 64);
            if (tid < 32) {
                uint_t pk = lo | (hi << 16);
                m2_s[tid] = pk;
                mh32[(t * 16 + b) * 32 + tid] = pk;   // plain store; no drain
            }
        }
        __syncthreads();   // sync3

        // ---- reload packed m (uniform-address broadcast reads) ----
        {
            const uint4* mg = (const uint4*)m2_s;
#pragma unroll
            for (int p = 0; p < 8; ++p) {
                uint4 v = mg[p];
                mreg2u[p * 4 + 0] = v.x;
                mreg2u[p * 4 + 1] = v.y;
                mreg2u[p * 4 + 2] = v.z;
                mreg2u[p * 4 + 3] = v.w;
            }
        }
    }
}

// ---------------- K5: parallel loss (reads f16 m history) ----------------
__global__ __launch_bounds__(256) void loss_kernel(
    const us_t* __restrict__ mhb, const us_t* __restrict__ decwY,
    const float* __restrict__ decb, const int* __restrict__ x0,
    float* __restrict__ out) {
    __shared__ __align__(16) us_t dw[16384];   // [mm][lane][k<4] bf16
    const int tid = threadIdx.x;
    {
        const uint4* g4 = (const uint4*)decwY;
        uint4* l4 = (uint4*)dw;
        for (int k = tid; k < 2048; k += 256) l4[k] = g4[k];
    }
    __syncthreads();
    const int lane = tid & 63, wv = tid >> 6;
    const uint2* dwu2 = (const uint2*)dw;
    float b0 = decb[lane], b1 = decb[lane + 64];
    float b2 = decb[lane + 128], b3 = decb[lane + 192];
    for (int r = 0; r < 8; ++r) {
        int row = blockIdx.x * 32 + wv * 8 + r;
        float mL = h2f(mhb[row * 64 + lane]);
        float l0 = b0, l1 = b1, l2 = b2, l3 = b3;
#pragma unroll
        for (int mm = 0; mm < 64; ++mm) {
            float mv = __shfl(mL, mm, 64);
            uint2 qq = dwu2[mm * 64 + lane];
            l0 += mv * bflo(qq.x);
            l1 += mv * bfhi(qq.x);
            l2 += mv * bflo(qq.y);
            l3 += mv * bfhi(qq.y);
        }
        float mx = fmaxf(fmaxf(l0, l1), fmaxf(l2, l3));
#pragma unroll
        for (int o = 32; o > 0; o >>= 1) mx = fmaxf(mx, __shfl_xor(mx, o, 64));
        float se = __expf(l0 - mx) + __expf(l1 - mx) + __expf(l2 - mx) + __expf(l3 - mx);
#pragma unroll
        for (int o = 32; o > 0; o >>= 1) se += __shfl_xor(se, o, 64);
        float lse = mx + __logf(se);
        int t = row >> 4, bb = row & 15;
        int y = x0[bb * 2048 + t];
        int hi = y >> 6;
        float cand = hi == 0 ? l0 : (hi == 1 ? l1 : (hi == 2 ? l2 : l3));
        float ly = __shfl(cand, y & 63, 64);
        if (lane == 0) out[row] = (lse - ly) * 1.4426950408889634f;
    }
}

extern "C" void kernel_launch(void* const* d_in, const int* in_sizes, int n_in,
                              void* d_out, int out_size, void* d_ws, size_t ws_size,
                              hipStream_t stream) {
    const int*   x0    = (const int*)d_in[0];
    const float* emb   = (const float*)d_in[1];
    const float* Wencw = (const float*)d_in[2];
    const float* Wencb = (const float*)d_in[3];
    const float* Wdecw = (const float*)d_in[4];
    const float* Wdecb = (const float*)d_in[5];
    const float* bencw = (const float*)d_in[6];
    const float* bencb = (const float*)d_in[7];
    const float* bdecw = (const float*)d_in[8];
    const float* bdecb = (const float*)d_in[9];
    const float* decw  = (const float*)d_in[10];
    const float* decb  = (const float*)d_in[11];
    float* out = (float*)d_out;

    char* ws = (char*)d_ws;
    us_t*   WdG   = (us_t*)(ws);                 //       0 .. 524288
    us_t*   decwY = (us_t*)(ws + 524288);        //  524288 .. 557056
    us_t*   EWmG  = (us_t*)(ws + 557056);        //  557056 .. 573440 (16 KB)
    float*  T     = (float*)(ws + 573440);       //  573440 .. 8962048 (8 MB)
    uint_t* mh32  = (uint_t*)T;                  //  alias: T dead after build_P (4 MB)
    float*  P     = (float*)(ws + 8962048);      // 8962048 .. 25739264 (16 MB)

    static const int kRecurLds = 152320;
    (void)hipFuncSetAttribute((const void*)recur,
                              hipFuncAttributeMaxDynamicSharedMemorySize,
                              kRecurLds);

    cvt_kernel<<<1120, 256, 0, stream>>>(Wdecw, decw, Wencw, bencw,
                                         WdG, decwY, EWmG);
    build_T<<<16384, 128, 0, stream>>>(emb, Wencw, bencw, T);
    build_P<<<32768, 128, 0, stream>>>(T, x0, Wencb, bencb, P);
    recur<<<16, 512, kRecurLds, stream>>>(bdecw, bdecb, Wdecb, WdG, EWmG,
                                          P, mh32);
    loss_kernel<<<1024, 256, 0, stream>>>((const us_t*)mh32, decwY, decb, x0, out);
}